// Round 8
// baseline (304.697 us; speedup 1.0000x reference)
//
#include <hip/hip_runtime.h>
#include <hip/hip_fp16.h>
#include <math.h>

#define NEG_SLOPE 0.2f

typedef _Float16 h8 __attribute__((ext_vector_type(8)));
typedef float f4 __attribute__((ext_vector_type(4)));

// ---------------- fp16 pack/unpack helpers ----------------

__device__ inline float2 up2(unsigned u) {
    __half2 h;
    __builtin_memcpy(&h, &u, 4);
    return __half22float2(h);
}
__device__ inline unsigned pk2(float a, float b) {
    __half2 h = __floats2half2_rn(a, b);
    unsigned u;
    __builtin_memcpy(&u, &h, 4);
    return u;
}
__device__ inline void fma8(float* acc, const uint4& v, float p) {
    float2 f;
    f = up2(v.x); acc[0] += f.x * p; acc[1] += f.y * p;
    f = up2(v.y); acc[2] += f.x * p; acc[3] += f.y * p;
    f = up2(v.z); acc[4] += f.x * p; acc[5] += f.y * p;
    f = up2(v.w); acc[6] += f.x * p; acc[7] += f.y * p;
}
__device__ inline float dot4(const float4& a, const float4& b) {
    return a.x * b.x + a.y * b.y + a.z * b.z + a.w * b.w;
}

// ---------------- prep: zero deg + pack W (fp16 fragment-major) + pad al2/ar2 ----
// W element (k,m): cfrag c=m>>4, kstep s=k>>5, lane=((k>>3)&3)*16 + (m&15), j=k&7

__global__ __launch_bounds__(256) void prep(const float* __restrict__ W0,
                                            const float* __restrict__ W1,
                                            const float* __restrict__ W2,
                                            const float* __restrict__ al2,
                                            const float* __restrict__ ar2,
                                            __half* __restrict__ P0,
                                            __half* __restrict__ P1,
                                            __half* __restrict__ P2,
                                            float* __restrict__ al2p,
                                            float* __restrict__ ar2p,
                                            int* __restrict__ deg, int N) {
    int b = blockIdx.x;
    int gtid = b * 256 + threadIdx.x;
    for (int i = gtid; i < N; i += gridDim.x * 256) deg[i] = 0;

    if (b < 14) {
        const float* W;
        __half* P;
        int K, M, Msrc, lb = b;
        if (lb < 8) {
            W = W0; P = P0; K = 128; M = 128; Msrc = 128;
        } else if (lb < 12) {
            W = W1; P = P1; K = 128; M = 64; Msrc = 64; lb -= 8;
        } else {
            W = W2; P = P2; K = 64; M = 64; Msrc = 40; lb -= 12;
        }
        int t = lb * 256 + threadIdx.x;  // indexes (m, k8)
        int nk8 = K >> 3;
        if (t < M * nk8) {
            int m = t % M, k8 = t / M;
            int k = k8 * 8;
            int c = m >> 4, s = k >> 5, hi = (k >> 3) & 3, lane = hi * 16 + (m & 15);
            float v[8];
#pragma unroll
            for (int i = 0; i < 8; ++i)
                v[i] = (m < Msrc) ? W[(size_t)(k + i) * Msrc + m] : 0.f;
            uint4 o;
            o.x = pk2(v[0], v[1]);
            o.y = pk2(v[2], v[3]);
            o.z = pk2(v[4], v[5]);
            o.w = pk2(v[6], v[7]);
            *(uint4*)(P + (size_t)((c * (K >> 5) + s) * 64 + lane) * 8) = o;
        }
    } else if (b == 14) {
        int t = threadIdx.x;
        if (t < 64) {
            al2p[t] = (t < 40) ? al2[t] : 0.f;
            ar2p[t] = (t < 40) ? ar2[t] : 0.f;
        }
    }
}

// ---------------- CSR build ----------------

__global__ __launch_bounds__(256) void degree_hist_rank(const int* __restrict__ dst,
                                                        int* __restrict__ deg,
                                                        int* __restrict__ rank, int E) {
    int e = blockIdx.x * blockDim.x + threadIdx.x;
    if (e >= E) return;
    int d = __builtin_nontemporal_load(&dst[e]);
    int r = atomicAdd(&deg[d], 1);
    __builtin_nontemporal_store(r, &rank[e]);
}

__global__ __launch_bounds__(256) void scan_block_sums(const int* __restrict__ in,
                                                       int* __restrict__ partial, int n) {
    int i = blockIdx.x * 256 + threadIdx.x;
    int v = (i < n) ? in[i] : 0;
#pragma unroll
    for (int off = 32; off; off >>= 1) v += __shfl_xor(v, off);
    __shared__ int wsum[4];
    if ((threadIdx.x & 63) == 0) wsum[threadIdx.x >> 6] = v;
    __syncthreads();
    if (threadIdx.x == 0) partial[blockIdx.x] = wsum[0] + wsum[1] + wsum[2] + wsum[3];
}

// merged offsets+final scan; each block reduces partial[0..bid) itself (nb<=256).
__global__ __launch_bounds__(256) void scan_final2(const int* __restrict__ in,
                                                   const int* __restrict__ partial,
                                                   int* __restrict__ out, int n) {
    __shared__ int buf[256];
    __shared__ int wsum[4];
    int t = threadIdx.x;
    int i = blockIdx.x * 256 + t;
    int v = (i < n) ? in[i] : 0;
    buf[t] = v;
    __syncthreads();
    for (int off = 1; off < 256; off <<= 1) {
        int x = (t >= off) ? buf[t - off] : 0;
        __syncthreads();
        buf[t] += x;
        __syncthreads();
    }
    int incl = buf[t];
    int pv = (t < blockIdx.x) ? partial[t] : 0;
#pragma unroll
    for (int off = 32; off; off >>= 1) pv += __shfl_xor(pv, off);
    if ((t & 63) == 0) wsum[t >> 6] = pv;
    __syncthreads();
    int pre = wsum[0] + wsum[1] + wsum[2] + wsum[3];
    if (i < n) out[i] = pre + incl - v;
    if (i == n - 1) out[n] = pre + incl;
}

__global__ __launch_bounds__(256) void scatter_rank(const int* __restrict__ src,
                                                    const int* __restrict__ dst,
                                                    const int* __restrict__ rank,
                                                    const int* __restrict__ row_start,
                                                    int* __restrict__ csr_src, int E) {
    int e = blockIdx.x * blockDim.x + threadIdx.x;
    if (e >= E) return;
    int d = __builtin_nontemporal_load(&dst[e]);
    int s = __builtin_nontemporal_load(&src[e]);
    int r = __builtin_nontemporal_load(&rank[e]);
    csr_src[row_start[d] + r] = s;
}

// ---------------- MFMA GEMM + fused attn-score epilogue ----------------
// 4 waves/block, 16 rows/wave, 64 rows/block. B fragments read straight from
// packed global W (L1/L2 resident); no inter-wave LDS sharing -> no barriers.
// A frag: row=lane&15, k=(lane>>4)*8+j.  D frag: col=lane&15, row=(lane>>4)*4+r.

template <int K, int M, int H, bool A16>
__global__ __launch_bounds__(256) void gemm_mfma(const void* __restrict__ xin,
                                                 const __half* __restrict__ Wp,
                                                 const float* __restrict__ al,
                                                 const float* __restrict__ ar,
                                                 __half* __restrict__ outh,
                                                 float* __restrict__ el,
                                                 float* __restrict__ er, int N) {
    constexpr int KS = K / 32;   // k-steps
    constexpr int CF = M / 16;   // column fragments
    constexpr int LDT = 133;     // padded fp32 LDS row stride
    constexpr int CH8 = M / 8;   // 8-col chunks per row
    constexpr int NC8 = CH8 / 4; // chunks per lane in read-back (4 lanes/row)
    __shared__ float tl[4 * 16 * LDT];
    const int tid = threadIdx.x;
    const int wid = tid >> 6, lane = tid & 63;
    const int lhi = lane >> 4, llo = lane & 15;
    const int rowbase = blockIdx.x * 64 + wid * 16;
    float* wt = tl + wid * 16 * LDT;

    f4 acc[CF];
#pragma unroll
    for (int c = 0; c < CF; ++c) acc[c] = f4{0.f, 0.f, 0.f, 0.f};

    const int arow = rowbase + llo;
    const bool aval = arow < N;
#pragma unroll
    for (int s = 0; s < KS; ++s) {
        h8 a = {};
        if (aval) {
            if constexpr (A16) {
                const __half* xp = (const __half*)xin + (size_t)arow * K + s * 32 + lhi * 8;
                a = *(const h8*)xp;
            } else {
                const float4* xp = (const float4*)((const float*)xin + (size_t)arow * K +
                                                   s * 32 + lhi * 8);
                float4 x0 = xp[0];
                float4 x1 = xp[1];
                a[0] = (_Float16)x0.x; a[1] = (_Float16)x0.y;
                a[2] = (_Float16)x0.z; a[3] = (_Float16)x0.w;
                a[4] = (_Float16)x1.x; a[5] = (_Float16)x1.y;
                a[6] = (_Float16)x1.z; a[7] = (_Float16)x1.w;
            }
        }
#pragma unroll
        for (int c = 0; c < CF; ++c) {
            h8 b = *(const h8*)(Wp + (size_t)((c * KS + s) * 64 + lane) * 8);
            acc[c] = __builtin_amdgcn_mfma_f32_16x16x32_f16(a, b, acc[c], 0, 0, 0);
        }
    }

    // scatter D frags into the per-wave LDS tile (row = lhi*4+r, col = c*16+llo)
#pragma unroll
    for (int c = 0; c < CF; ++c) {
#pragma unroll
        for (int r = 0; r < 4; ++r)
            wt[(lhi * 4 + r) * LDT + c * 16 + llo] = acc[c][r];
    }

    // read back row-major: 4 lanes per row, interleaved 8-col chunks j8 = q + 4*i
    const int rrow = lane >> 2;
    const int q = lane & 3;
    const int grow = rowbase + rrow;
    float elp[H], erp[H];
#pragma unroll
    for (int h = 0; h < H; ++h) { elp[h] = 0.f; erp[h] = 0.f; }
    const float4* al4 = (const float4*)al;
    const float4* ar4 = (const float4*)ar;
#pragma unroll
    for (int i = 0; i < NC8; ++i) {
        int j8 = q + 4 * i;
        float4 v0 = *(float4*)&wt[rrow * LDT + 8 * j8];
        float4 v1 = *(float4*)&wt[rrow * LDT + 8 * j8 + 4];
        int h = (H == 2 && i >= NC8 / 2) ? 1 : 0;
        float4 a0 = al4[2 * j8], a1 = al4[2 * j8 + 1];
        float4 r0 = ar4[2 * j8], r1 = ar4[2 * j8 + 1];
        elp[h] += dot4(v0, a0) + dot4(v1, a1);
        erp[h] += dot4(v0, r0) + dot4(v1, r1);
        if (grow < N) {
            uint4 pkv;
            pkv.x = pk2(v0.x, v0.y);
            pkv.y = pk2(v0.z, v0.w);
            pkv.z = pk2(v1.x, v1.y);
            pkv.w = pk2(v1.z, v1.w);
            *(uint4*)(outh + (size_t)grow * M + 8 * j8) = pkv;
        }
    }
#pragma unroll
    for (int h = 0; h < H; ++h) {
#pragma unroll
        for (int off = 1; off < 4; off <<= 1) {
            elp[h] += __shfl_xor(elp[h], off);
            erp[h] += __shfl_xor(erp[h], off);
        }
    }
    if (q == 0 && grow < N) {
        if constexpr (H == 2) {
            *(float2*)&el[(size_t)grow * 2] = float2{elp[0], elp[1]};
            *(float2*)&er[(size_t)grow * 2] = float2{erp[0], erp[1]};
        } else {
            el[grow] = elp[0];
            er[grow] = erp[0];
        }
    }
}

// ---------------- per-dst softmax + aggregation (HALF-wave per dst) ----------------
// Per 32-edge trip (DS-minimized):
//   (1) lane-parallel csr_src + el[s] loads (el = oldest outstanding vmem)
//   (2) per-group DIRECT csr_src broadcast loads (L1-hot line) -> row gathers
//   (3) scores: waits only el; p -> per-wave LDS table (1 ds_write)
//   (4) fma: p read back via ds_read_b32 broadcast (conflict-free)
// DS ops/trip: L0 48 -> 17, L1/L2 16 -> 9; vmem chain depth unchanged.

template <int H, int D, int FSTRIDE, int T, bool OUT16>
__global__ __launch_bounds__(256) void gat_aggregate4(const __half* __restrict__ feat,
                                                      const float* __restrict__ el,
                                                      const float* __restrict__ er,
                                                      const int* __restrict__ row_start,
                                                      const int* __restrict__ csr_src,
                                                      const float* __restrict__ bias,
                                                      void* __restrict__ out, int N) {
    constexpr int NLp = FSTRIDE / 8;   // lanes per padded row (uint4 each)
    constexpr int GnH = 32 / NLp;      // edge groups per half-wave
    constexpr int BATCH = GnH * T;     // edges per gather round per half
    constexpr int WL = (H * D) / 8;    // writer lanes per dst
    static_assert(32 % NLp == 0 && BATCH == 32, "whole trip in one round");
    __shared__ float ptab[4][64 * H];  // per-wave p table (no cross-wave sharing)
    int pair = (blockIdx.x * blockDim.x + threadIdx.x) >> 6;
    int lane = threadIdx.x & 63;
    if (pair * 2 >= N) return;
    const int wid = threadIdx.x >> 6;
    const int l32 = lane & 31;
    const int hb = lane & 32;
    const int dstn = pair * 2 + (lane >> 5);
    const bool dval = dstn < N;
    float* pt = ptab[wid];
    int beg = dval ? row_start[dstn] : 0;
    int end = dval ? row_start[dstn + 1] : 0;
    int cnt = end - beg;

    float er_d[H];
#pragma unroll
    for (int h = 0; h < H; ++h) er_d[h] = dval ? er[(size_t)dstn * H + h] : 0.f;

    float ssum[H];
    float acc8[8];
#pragma unroll
    for (int h = 0; h < H; ++h) ssum[h] = 0.f;
#pragma unroll
    for (int i = 0; i < 8; ++i) acc8[i] = 0.f;

    const int g = l32 / NLp;
    const int ln = l32 % NLp;
    const uint4* fp = (const uint4*)feat;

    int trips = (cnt + 31) >> 5;
    {
        int to = __shfl_xor(trips, 32);
        trips = (to > trips) ? to : trips;
    }

    for (int it = 0; it < trips; ++it) {
        int base = beg + it * 32;
        int idx = base + l32;
        bool valid = idx < end;
        int s = csr_src[valid ? idx : beg];
        int cc = end - base;
        cc = (cc < 0) ? 0 : ((cc > 32) ? 32 : cc);

        // (1) score-input load: oldest outstanding vmem op
        float ev0 = 0.f, ev1 = 0.f;
        if constexpr (H == 2) {
            float2 e2 = ((const float2*)el)[s];
            ev0 = e2.x;
            ev1 = e2.y;
        } else {
            ev0 = el[s];
        }

        // (2) per-group direct csr broadcast (L1-hot) + row gathers
        uint4 v[T];
#pragma unroll
        for (int t = 0; t < T; ++t) {
            int sl = GnH * t + g;
            if (sl < cc) {
                int sj = csr_src[base + sl];  // same line as step-(1) load -> L1 hit
                v[t] = fp[(size_t)sj * NLp + ln];
            }
        }

        // (3) scores: waits only on el (gathers remain in flight); publish to LDS
        if constexpr (H == 2) {
            float e0 = ev0 + er_d[0];
            float e1 = ev1 + er_d[1];
            e0 = (e0 > 0.f) ? e0 : NEG_SLOPE * e0;
            e1 = (e1 > 0.f) ? e1 : NEG_SLOPE * e1;
            float p0 = valid ? __expf(e0) : 0.f;
            float p1 = valid ? __expf(e1) : 0.f;
            ssum[0] += p0;
            ssum[1] += p1;
            *(float2*)&pt[(hb + l32) * 2] = float2{p0, p1};
        } else {
            float e = ev0 + er_d[0];
            e = (e > 0.f) ? e : NEG_SLOPE * e;
            float p0 = valid ? __expf(e) : 0.f;
            ssum[0] += p0;
            pt[hb + l32] = p0;
        }
        asm volatile("" ::: "memory");  // pin ds_write before ds_reads (in-order DS)

        // (4) weighted accumulate; p via broadcast ds_read (conflict-free)
#pragma unroll
        for (int t = 0; t < T; ++t) {
            int sl = GnH * t + g;
            if (sl < cc) {
                float pj;
                if constexpr (H == 2) pj = pt[(hb + sl) * 2 + (ln >= 8 ? 1 : 0)];
                else pj = pt[hb + sl];
                fma8(acc8, v[t], pj);
            }
        }
        asm volatile("" ::: "memory");  // reads of this trip before next trip's writes
    }

#pragma unroll
    for (int h = 0; h < H; ++h)
#pragma unroll
        for (int off = 16; off; off >>= 1) ssum[h] += __shfl_xor(ssum[h], off);
#pragma unroll
    for (int i = 0; i < 8; ++i) {
#pragma unroll
        for (int off = NLp; off < 32; off <<= 1) acc8[i] += __shfl_xor(acc8[i], off);
    }
    if (l32 < WL && dval) {
        float inv;
        if constexpr (H == 2) inv = 1.f / ((l32 >= 8) ? ssum[1] : ssum[0]);
        else inv = 1.f / ssum[0];
        const float4* bp = (const float4*)bias;
        float4 bv0 = bp[2 * l32], bv1 = bp[2 * l32 + 1];
        float4 o0, o1;
        o0.x = acc8[0] * inv + bv0.x; o0.y = acc8[1] * inv + bv0.y;
        o0.z = acc8[2] * inv + bv0.z; o0.w = acc8[3] * inv + bv0.w;
        o1.x = acc8[4] * inv + bv1.x; o1.y = acc8[5] * inv + bv1.y;
        o1.z = acc8[6] * inv + bv1.z; o1.w = acc8[7] * inv + bv1.w;
        if constexpr (OUT16) {
            __half* op = (__half*)out + (size_t)dstn * (H * D);
            uint4 pkv;
            pkv.x = pk2(o0.x, o0.y);
            pkv.y = pk2(o0.z, o0.w);
            pkv.z = pk2(o1.x, o1.y);
            pkv.w = pk2(o1.z, o1.w);
            ((uint4*)op)[l32] = pkv;
        } else {
            float4* op = (float4*)((float*)out + (size_t)dstn * (H * D));
            op[2 * l32] = o0;
            op[2 * l32 + 1] = o1;
        }
    }
}

// ---------------- launch ----------------

extern "C" void kernel_launch(void* const* d_in, const int* in_sizes, int n_in,
                              void* d_out, int out_size, void* d_ws, size_t ws_size,
                              hipStream_t stream) {
    const float* in_feat = (const float*)d_in[0];
    const int*   src     = (const int*)d_in[1];
    const int*   dst     = (const int*)d_in[2];
    const float* W0 = (const float*)d_in[3];
    const float* al0 = (const float*)d_in[4];
    const float* ar0 = (const float*)d_in[5];
    const float* b0 = (const float*)d_in[6];
    const float* W1 = (const float*)d_in[7];
    const float* al1 = (const float*)d_in[8];
    const float* ar1 = (const float*)d_in[9];
    const float* b1 = (const float*)d_in[10];
    const float* W2 = (const float*)d_in[11];
    const float* al2 = (const float*)d_in[12];
    const float* ar2 = (const float*)d_in[13];
    const float* b2 = (const float*)d_in[14];
    float* out = (float*)d_out;

    const int N = in_sizes[0] / 128;  // 50000
    const int E = in_sizes[1];        // 850000

    char* ws = (char*)d_ws;
    auto alloc = [&](size_t bytes) -> void* {
        void* p = (void*)ws;
        ws += (bytes + 255) & ~(size_t)255;
        return p;
    };
    int* deg       = (int*)alloc((size_t)N * 4);
    int* row_start = (int*)alloc((size_t)(N + 1) * 4);
    int* csr_src   = (int*)alloc((size_t)E * 4);
    int* rank      = (int*)alloc((size_t)E * 4);
    int* partial   = (int*)alloc(256 * 4);
    __half* feat   = (__half*)alloc((size_t)N * 128 * 2);
    float* el      = (float*)alloc((size_t)N * 2 * 4);
    float* er      = (float*)alloc((size_t)N * 2 * 4);
    __half* h0h    = (__half*)alloc((size_t)N * 128 * 2);
    __half* h1h    = (__half*)alloc((size_t)N * 64 * 2);
    __half* Wp0    = (__half*)alloc((size_t)128 * 128 * 2);
    __half* Wp1    = (__half*)alloc((size_t)128 * 64 * 2);
    __half* Wp2    = (__half*)alloc((size_t)64 * 64 * 2);
    float* al2p    = (float*)alloc(64 * 4);
    float* ar2p    = (float*)alloc(64 * 4);

    int egrid = (E + 255) / 256;
    int nb = (N + 255) / 256;

    prep<<<256, 256, 0, stream>>>(W0, W1, W2, al2, ar2, Wp0, Wp1, Wp2, al2p, ar2p, deg, N);
    degree_hist_rank<<<egrid, 256, 0, stream>>>(dst, deg, rank, E);
    scan_block_sums<<<nb, 256, 0, stream>>>(deg, partial, N);
    scan_final2<<<nb, 256, 0, stream>>>(deg, partial, row_start, N);
    scatter_rank<<<egrid, 256, 0, stream>>>(src, dst, rank, row_start, csr_src, E);

    int npairs = (N + 1) / 2;
    int pgrid = (npairs * 64 + 255) / 256;  // one wave per dst-pair
    int mgrid = (N + 63) / 64;              // 64 rows per MFMA gemm block

    // layer 0: in=128(fp32), M=128, H=2  | agg: FSTRIDE=128 -> T=16 (BATCH=32)
    gemm_mfma<128, 128, 2, false><<<mgrid, 256, 0, stream>>>(in_feat, Wp0, al0, ar0, feat, el, er, N);
    gat_aggregate4<2, 64, 128, 16, true><<<pgrid, 256, 0, stream>>>(feat, el, er, row_start, csr_src, b0, h0h, N);

    // layer 1: in=128(fp16), M=64, H=1   | agg: FSTRIDE=64 -> T=8 (BATCH=32)
    gemm_mfma<128, 64, 1, true><<<mgrid, 256, 0, stream>>>(h0h, Wp1, al1, ar1, feat, el, er, N);
    gat_aggregate4<1, 64, 64, 8, true><<<pgrid, 256, 0, stream>>>(feat, el, er, row_start, csr_src, b1, h1h, N);

    // layer 2: in=64(fp16), M=64 (cols 40-63 exact zeros), H=1
    gemm_mfma<64, 64, 1, true><<<mgrid, 256, 0, stream>>>(h1h, Wp2, al2p, ar2p, feat, el, er, N);
    gat_aggregate4<1, 40, 64, 8, false><<<pgrid, 256, 0, stream>>>(feat, el, er, row_start, csr_src, b2, out, N);
}

// Round 9
// 282.697 us; speedup vs baseline: 1.0778x; 1.0778x over previous
//
#include <hip/hip_runtime.h>
#include <hip/hip_fp16.h>
#include <math.h>

#define NEG_SLOPE 0.2f

typedef _Float16 h8 __attribute__((ext_vector_type(8)));
typedef float f4 __attribute__((ext_vector_type(4)));

// ---------------- fp16 pack/unpack helpers ----------------

__device__ inline float2 up2(unsigned u) {
    __half2 h;
    __builtin_memcpy(&h, &u, 4);
    return __half22float2(h);
}
__device__ inline unsigned pk2(float a, float b) {
    __half2 h = __floats2half2_rn(a, b);
    unsigned u;
    __builtin_memcpy(&u, &h, 4);
    return u;
}
__device__ inline void fma8(float* acc, const uint4& v, float p) {
    float2 f;
    f = up2(v.x); acc[0] += f.x * p; acc[1] += f.y * p;
    f = up2(v.y); acc[2] += f.x * p; acc[3] += f.y * p;
    f = up2(v.z); acc[4] += f.x * p; acc[5] += f.y * p;
    f = up2(v.w); acc[6] += f.x * p; acc[7] += f.y * p;
}
__device__ inline float dot4(const float4& a, const float4& b) {
    return a.x * b.x + a.y * b.y + a.z * b.z + a.w * b.w;
}

// ---------------- prep: zero deg + pack W (fp16 fragment-major) + pad al2/ar2 ----
// W element (k,m): cfrag c=m>>4, kstep s=k>>5, lane=((k>>3)&3)*16 + (m&15), j=k&7

__global__ __launch_bounds__(256) void prep(const float* __restrict__ W0,
                                            const float* __restrict__ W1,
                                            const float* __restrict__ W2,
                                            const float* __restrict__ al2,
                                            const float* __restrict__ ar2,
                                            __half* __restrict__ P0,
                                            __half* __restrict__ P1,
                                            __half* __restrict__ P2,
                                            float* __restrict__ al2p,
                                            float* __restrict__ ar2p,
                                            int* __restrict__ deg, int N) {
    int b = blockIdx.x;
    int gtid = b * 256 + threadIdx.x;
    for (int i = gtid; i < N; i += gridDim.x * 256) deg[i] = 0;

    if (b < 14) {
        const float* W;
        __half* P;
        int K, M, Msrc, lb = b;
        if (lb < 8) {
            W = W0; P = P0; K = 128; M = 128; Msrc = 128;
        } else if (lb < 12) {
            W = W1; P = P1; K = 128; M = 64; Msrc = 64; lb -= 8;
        } else {
            W = W2; P = P2; K = 64; M = 64; Msrc = 40; lb -= 12;
        }
        int t = lb * 256 + threadIdx.x;  // indexes (m, k8)
        int nk8 = K >> 3;
        if (t < M * nk8) {
            int m = t % M, k8 = t / M;
            int k = k8 * 8;
            int c = m >> 4, s = k >> 5, hi = (k >> 3) & 3, lane = hi * 16 + (m & 15);
            float v[8];
#pragma unroll
            for (int i = 0; i < 8; ++i)
                v[i] = (m < Msrc) ? W[(size_t)(k + i) * Msrc + m] : 0.f;
            uint4 o;
            o.x = pk2(v[0], v[1]);
            o.y = pk2(v[2], v[3]);
            o.z = pk2(v[4], v[5]);
            o.w = pk2(v[6], v[7]);
            *(uint4*)(P + (size_t)((c * (K >> 5) + s) * 64 + lane) * 8) = o;
        }
    } else if (b == 14) {
        int t = threadIdx.x;
        if (t < 64) {
            al2p[t] = (t < 40) ? al2[t] : 0.f;
            ar2p[t] = (t < 40) ? ar2[t] : 0.f;
        }
    }
}

// ---------------- CSR build ----------------

__global__ __launch_bounds__(256) void degree_hist_rank(const int* __restrict__ dst,
                                                        int* __restrict__ deg,
                                                        int* __restrict__ rank, int E) {
    int e = blockIdx.x * blockDim.x + threadIdx.x;
    if (e >= E) return;
    int d = __builtin_nontemporal_load(&dst[e]);
    int r = atomicAdd(&deg[d], 1);
    __builtin_nontemporal_store(r, &rank[e]);
}

// single-kernel exclusive scan (nb = 196 blocks): each block computes its chunk's
// local prefix AND reduces deg[0 .. b*256) itself (L2-hot) -> no partial pass.
__global__ __launch_bounds__(256) void scan_one(const int* __restrict__ deg,
                                                int* __restrict__ out, int n) {
    __shared__ int buf[256];
    __shared__ int wsum[4];
    int t = threadIdx.x;
    int b = blockIdx.x;
    int i = b * 256 + t;
    int v = (i < n) ? deg[i] : 0;
    buf[t] = v;
    __syncthreads();
    for (int off = 1; off < 256; off <<= 1) {
        int x = (t >= off) ? buf[t - off] : 0;
        __syncthreads();
        buf[t] += x;
        __syncthreads();
    }
    int incl = buf[t];
    int pv = 0;
    for (int j = t; j < b * 256; j += 256) pv += deg[j];
#pragma unroll
    for (int off = 32; off; off >>= 1) pv += __shfl_xor(pv, off);
    if ((t & 63) == 0) wsum[t >> 6] = pv;
    __syncthreads();
    int pre = wsum[0] + wsum[1] + wsum[2] + wsum[3];
    if (i < n) out[i] = pre + incl - v;
    if (i == n - 1) out[n] = pre + incl;
}

// ---------------- GEMM tile (device): 16 rows per wave ----------------
// B frags from packed global W (L1/L2 resident); no inter-wave LDS -> no barriers.
// A frag: row=lane&15, k=(lane>>4)*8+j.  D frag: col=lane&15, row=(lane>>4)*4+r.

template <int K, int M, int H, bool A16>
__device__ __forceinline__ void dev_gemm(float* wt, const void* __restrict__ xin,
                                         const __half* __restrict__ Wp,
                                         const float* __restrict__ al,
                                         const float* __restrict__ ar,
                                         __half* __restrict__ outh,
                                         float* __restrict__ el,
                                         float* __restrict__ er, int rowbase, int N) {
    constexpr int KS = K / 32;   // k-steps
    constexpr int CF = M / 16;   // column fragments
    constexpr int LDT = 133;     // padded fp32 LDS row stride
    constexpr int NC8 = (M / 8) / 4;  // 8-col chunks per lane (4 lanes/row)
    const int lane = threadIdx.x & 63;
    const int lhi = lane >> 4, llo = lane & 15;

    f4 acc[CF];
#pragma unroll
    for (int c = 0; c < CF; ++c) acc[c] = f4{0.f, 0.f, 0.f, 0.f};

    const int arow = rowbase + llo;
    const bool aval = arow < N;
#pragma unroll
    for (int s = 0; s < KS; ++s) {
        h8 a = {};
        if (aval) {
            if constexpr (A16) {
                const __half* xp = (const __half*)xin + (size_t)arow * K + s * 32 + lhi * 8;
                a = *(const h8*)xp;
            } else {
                const float4* xp = (const float4*)((const float*)xin + (size_t)arow * K +
                                                   s * 32 + lhi * 8);
                float4 x0 = xp[0];
                float4 x1 = xp[1];
                a[0] = (_Float16)x0.x; a[1] = (_Float16)x0.y;
                a[2] = (_Float16)x0.z; a[3] = (_Float16)x0.w;
                a[4] = (_Float16)x1.x; a[5] = (_Float16)x1.y;
                a[6] = (_Float16)x1.z; a[7] = (_Float16)x1.w;
            }
        }
#pragma unroll
        for (int c = 0; c < CF; ++c) {
            h8 b = *(const h8*)(Wp + (size_t)((c * KS + s) * 64 + lane) * 8);
            acc[c] = __builtin_amdgcn_mfma_f32_16x16x32_f16(a, b, acc[c], 0, 0, 0);
        }
    }

    // scatter D frags into the per-wave LDS tile (row = lhi*4+r, col = c*16+llo)
#pragma unroll
    for (int c = 0; c < CF; ++c) {
#pragma unroll
        for (int r = 0; r < 4; ++r)
            wt[(lhi * 4 + r) * LDT + c * 16 + llo] = acc[c][r];
    }
    // same-wave LDS RAW: compiler inserts lgkmcnt; no barrier needed

    // read back row-major: 4 lanes per row, interleaved 8-col chunks j8 = q + 4*i
    const int rrow = lane >> 2;
    const int q = lane & 3;
    const int grow = rowbase + rrow;
    float elp[H], erp[H];
#pragma unroll
    for (int h = 0; h < H; ++h) { elp[h] = 0.f; erp[h] = 0.f; }
    const float4* al4 = (const float4*)al;
    const float4* ar4 = (const float4*)ar;
#pragma unroll
    for (int i = 0; i < NC8; ++i) {
        int j8 = q + 4 * i;
        float4 v0 = *(float4*)&wt[rrow * LDT + 8 * j8];
        float4 v1 = *(float4*)&wt[rrow * LDT + 8 * j8 + 4];
        int h = (H == 2 && i >= NC8 / 2) ? 1 : 0;
        float4 a0 = al4[2 * j8], a1 = al4[2 * j8 + 1];
        float4 r0 = ar4[2 * j8], r1 = ar4[2 * j8 + 1];
        elp[h] += dot4(v0, a0) + dot4(v1, a1);
        erp[h] += dot4(v0, r0) + dot4(v1, r1);
        if (grow < N) {
            uint4 pkv;
            pkv.x = pk2(v0.x, v0.y);
            pkv.y = pk2(v0.z, v0.w);
            pkv.z = pk2(v1.x, v1.y);
            pkv.w = pk2(v1.z, v1.w);
            *(uint4*)(outh + (size_t)grow * M + 8 * j8) = pkv;
        }
    }
#pragma unroll
    for (int h = 0; h < H; ++h) {
#pragma unroll
        for (int off = 1; off < 4; off <<= 1) {
            elp[h] += __shfl_xor(elp[h], off);
            erp[h] += __shfl_xor(erp[h], off);
        }
    }
    if (q == 0 && grow < N) {
        if constexpr (H == 2) {
            *(float2*)&el[(size_t)grow * 2] = float2{elp[0], elp[1]};
            *(float2*)&er[(size_t)grow * 2] = float2{erp[0], erp[1]};
        } else {
            el[grow] = elp[0];
            er[grow] = erp[0];
        }
    }
}

// standalone gemm kernel (layers 1/2)
template <int K, int M, int H, bool A16>
__global__ __launch_bounds__(256) void gemm_mfma(const void* __restrict__ xin,
                                                 const __half* __restrict__ Wp,
                                                 const float* __restrict__ al,
                                                 const float* __restrict__ ar,
                                                 __half* __restrict__ outh,
                                                 float* __restrict__ el,
                                                 float* __restrict__ er, int N) {
    __shared__ float tl[4 * 16 * 133];
    const int wid = threadIdx.x >> 6;
    dev_gemm<K, M, H, A16>(tl + wid * 16 * 133, xin, Wp, al, ar, outh, el, er,
                           blockIdx.x * 64 + wid * 16, N);
}

// fused: rank-based CSR scatter (independent) + gemm layer 0.
// Scatter stores are fire-and-forget and drain under the MFMA work.
__global__ __launch_bounds__(256) void scatter_gemm0(
    const int* __restrict__ src, const int* __restrict__ dst,
    const int* __restrict__ rank, const int* __restrict__ row_start,
    int* __restrict__ csr_src,
    const float* __restrict__ in_feat, const __half* __restrict__ Wp0,
    const float* __restrict__ al0, const float* __restrict__ ar0,
    __half* __restrict__ feat0, float* __restrict__ el0, float* __restrict__ er0,
    int N, int E) {
    __shared__ float tl[4 * 16 * 133];
    int e = blockIdx.x * 256 + threadIdx.x;
    if (e < E) {
        int d = __builtin_nontemporal_load(&dst[e]);
        int s = __builtin_nontemporal_load(&src[e]);
        int r = __builtin_nontemporal_load(&rank[e]);
        csr_src[row_start[d] + r] = s;
    }
    const int ntiles = (N + 63) >> 6;
    if (blockIdx.x < ntiles) {
        const int wid = threadIdx.x >> 6;
        dev_gemm<128, 128, 2, false>(tl + wid * 16 * 133, in_feat, Wp0, al0, ar0,
                                     feat0, el0, er0, blockIdx.x * 64 + wid * 16, N);
    }
}

// ---------------- per-dst softmax + aggregation (HALF-wave per dst) ----------------
// R6-proven trip order:
//   (1) issue el[s] load (oldest outstanding vmem)
//   (2) issue ALL feature-row gathers for the trip (BATCH == 32)
//   (3) compute p  -> waits only el, gathers still in flight
//   (4) fma        -> waits gathers

template <int H, int D, int FSTRIDE, int T, bool OUT16>
__global__ __launch_bounds__(256) void gat_aggregate3(const __half* __restrict__ feat,
                                                      const float* __restrict__ el,
                                                      const float* __restrict__ er,
                                                      const int* __restrict__ row_start,
                                                      const int* __restrict__ csr_src,
                                                      const float* __restrict__ bias,
                                                      void* __restrict__ out, int N) {
    constexpr int NLp = FSTRIDE / 8;   // lanes per padded row (uint4 each)
    constexpr int GnH = 32 / NLp;      // edge groups per half-wave
    constexpr int BATCH = GnH * T;     // edges per gather round per half
    constexpr int WL = (H * D) / 8;    // writer lanes per dst
    static_assert(32 % NLp == 0 && BATCH == 32, "whole trip in one round");
    int pair = (blockIdx.x * blockDim.x + threadIdx.x) >> 6;
    int lane = threadIdx.x & 63;
    if (pair * 2 >= N) return;
    const int l32 = lane & 31;
    const int hb = lane & 32;
    const int dstn = pair * 2 + (lane >> 5);
    const bool dval = dstn < N;
    int beg = dval ? row_start[dstn] : 0;
    int end = dval ? row_start[dstn + 1] : 0;
    int cnt = end - beg;

    float er_d[H];
#pragma unroll
    for (int h = 0; h < H; ++h) er_d[h] = dval ? er[(size_t)dstn * H + h] : 0.f;

    float ssum[H];
    float acc8[8];
#pragma unroll
    for (int h = 0; h < H; ++h) ssum[h] = 0.f;
#pragma unroll
    for (int i = 0; i < 8; ++i) acc8[i] = 0.f;

    const int g = l32 / NLp;
    const int ln = l32 % NLp;
    const uint4* fp = (const uint4*)feat;

    int trips = (cnt + 31) >> 5;
    {
        int to = __shfl_xor(trips, 32);
        trips = (to > trips) ? to : trips;
    }

    for (int it = 0; it < trips; ++it) {
        int base = beg + it * 32;
        int idx = base + l32;
        bool valid = idx < end;
        int s = csr_src[valid ? idx : beg];
        int cc = end - base;
        cc = (cc < 0) ? 0 : ((cc > 32) ? 32 : cc);

        // (1) score-input load first: oldest outstanding vmem op
        float ev0 = 0.f, ev1 = 0.f;
        if constexpr (H == 2) {
            float2 e2 = ((const float2*)el)[s];
            ev0 = e2.x;
            ev1 = e2.y;
        } else {
            ev0 = el[s];
        }

        // (2) issue the whole trip's feature-row gathers (depend only on s)
        uint4 v[T];
#pragma unroll
        for (int t = 0; t < T; ++t) {
            if (GnH * t < cc) {
                int sj = __shfl(s, hb + GnH * t + g);
                v[t] = fp[(size_t)sj * NLp + ln];
            }
        }

        // (3) scores: waits only on el (gathers remain in flight)
        float p[H];
        if constexpr (H == 2) {
            float e0 = ev0 + er_d[0];
            float e1 = ev1 + er_d[1];
            e0 = (e0 > 0.f) ? e0 : NEG_SLOPE * e0;
            e1 = (e1 > 0.f) ? e1 : NEG_SLOPE * e1;
            p[0] = valid ? __expf(e0) : 0.f;
            p[1] = valid ? __expf(e1) : 0.f;
            ssum[0] += p[0];
            ssum[1] += p[1];
        } else {
            float e = ev0 + er_d[0];
            e = (e > 0.f) ? e : NEG_SLOPE * e;
            p[0] = valid ? __expf(e) : 0.f;
            ssum[0] += p[0];
        }

        // (4) weighted accumulate
#pragma unroll
        for (int t = 0; t < T; ++t) {
            if (GnH * t < cc) {
                int slot = hb + GnH * t + g;
                float pj = __shfl(p[0], slot);
                if constexpr (H == 2) {
                    float pj1 = __shfl(p[1], slot);
                    pj = (ln >= 8) ? pj1 : pj;
                }
                fma8(acc8, v[t], pj);
            }
        }
    }

#pragma unroll
    for (int h = 0; h < H; ++h)
#pragma unroll
        for (int off = 16; off; off >>= 1) ssum[h] += __shfl_xor(ssum[h], off);
#pragma unroll
    for (int i = 0; i < 8; ++i) {
#pragma unroll
        for (int off = NLp; off < 32; off <<= 1) acc8[i] += __shfl_xor(acc8[i], off);
    }
    if (l32 < WL && dval) {
        float inv;
        if constexpr (H == 2) inv = 1.f / ((l32 >= 8) ? ssum[1] : ssum[0]);
        else inv = 1.f / ssum[0];
        const float4* bp = (const float4*)bias;
        float4 bv0 = bp[2 * l32], bv1 = bp[2 * l32 + 1];
        float4 o0, o1;
        o0.x = acc8[0] * inv + bv0.x; o0.y = acc8[1] * inv + bv0.y;
        o0.z = acc8[2] * inv + bv0.z; o0.w = acc8[3] * inv + bv0.w;
        o1.x = acc8[4] * inv + bv1.x; o1.y = acc8[5] * inv + bv1.y;
        o1.z = acc8[6] * inv + bv1.z; o1.w = acc8[7] * inv + bv1.w;
        if constexpr (OUT16) {
            __half* op = (__half*)out + (size_t)dstn * (H * D);
            uint4 pkv;
            pkv.x = pk2(o0.x, o0.y);
            pkv.y = pk2(o0.z, o0.w);
            pkv.z = pk2(o1.x, o1.y);
            pkv.w = pk2(o1.z, o1.w);
            ((uint4*)op)[l32] = pkv;
        } else {
            float4* op = (float4*)((float*)out + (size_t)dstn * (H * D));
            op[2 * l32] = o0;
            op[2 * l32 + 1] = o1;
        }
    }
}

// ---------------- launch ----------------

extern "C" void kernel_launch(void* const* d_in, const int* in_sizes, int n_in,
                              void* d_out, int out_size, void* d_ws, size_t ws_size,
                              hipStream_t stream) {
    const float* in_feat = (const float*)d_in[0];
    const int*   src     = (const int*)d_in[1];
    const int*   dst     = (const int*)d_in[2];
    const float* W0 = (const float*)d_in[3];
    const float* al0 = (const float*)d_in[4];
    const float* ar0 = (const float*)d_in[5];
    const float* b0 = (const float*)d_in[6];
    const float* W1 = (const float*)d_in[7];
    const float* al1 = (const float*)d_in[8];
    const float* ar1 = (const float*)d_in[9];
    const float* b1 = (const float*)d_in[10];
    const float* W2 = (const float*)d_in[11];
    const float* al2 = (const float*)d_in[12];
    const float* ar2 = (const float*)d_in[13];
    const float* b2 = (const float*)d_in[14];
    float* out = (float*)d_out;

    const int N = in_sizes[0] / 128;  // 50000
    const int E = in_sizes[1];        // 850000

    char* ws = (char*)d_ws;
    auto alloc = [&](size_t bytes) -> void* {
        void* p = (void*)ws;
        ws += (bytes + 255) & ~(size_t)255;
        return p;
    };
    int* deg       = (int*)alloc((size_t)N * 4);
    int* row_start = (int*)alloc((size_t)(N + 1) * 4);
    int* csr_src   = (int*)alloc((size_t)E * 4);
    int* rank      = (int*)alloc((size_t)E * 4);
    __half* feat   = (__half*)alloc((size_t)N * 128 * 2);
    float* el      = (float*)alloc((size_t)N * 2 * 4);
    float* er      = (float*)alloc((size_t)N * 2 * 4);
    __half* h0h    = (__half*)alloc((size_t)N * 128 * 2);
    __half* h1h    = (__half*)alloc((size_t)N * 64 * 2);
    __half* Wp0    = (__half*)alloc((size_t)128 * 128 * 2);
    __half* Wp1    = (__half*)alloc((size_t)128 * 64 * 2);
    __half* Wp2    = (__half*)alloc((size_t)64 * 64 * 2);
    float* al2p    = (float*)alloc(64 * 4);
    float* ar2p    = (float*)alloc(64 * 4);

    int egrid = (E + 255) / 256;   // 3321
    int nb = (N + 255) / 256;      // 196

    prep<<<256, 256, 0, stream>>>(W0, W1, W2, al2, ar2, Wp0, Wp1, Wp2, al2p, ar2p, deg, N);
    degree_hist_rank<<<egrid, 256, 0, stream>>>(dst, deg, rank, E);
    scan_one<<<nb, 256, 0, stream>>>(deg, row_start, N);
    // CSR scatter (rank-based, atomic-free) + gemm L0 in one dispatch
    scatter_gemm0<<<egrid, 256, 0, stream>>>(src, dst, rank, row_start, csr_src,
                                             in_feat, Wp0, al0, ar0, feat, el, er, N, E);

    int npairs = (N + 1) / 2;
    int pgrid = (npairs * 64 + 255) / 256;  // one wave per dst-pair
    int mgrid = (N + 63) / 64;              // 64 rows per MFMA gemm block

    // agg L0: FSTRIDE=128 -> T=16 (BATCH=32)
    gat_aggregate3<2, 64, 128, 16, true><<<pgrid, 256, 0, stream>>>(feat, el, er, row_start, csr_src, b0, h0h, N);

    // layer 1: in=128(fp16), M=64, H=1   | agg: FSTRIDE=64 -> T=8 (BATCH=32)
    gemm_mfma<128, 64, 1, true><<<mgrid, 256, 0, stream>>>(h0h, Wp1, al1, ar1, feat, el, er, N);
    gat_aggregate3<1, 64, 64, 8, true><<<pgrid, 256, 0, stream>>>(feat, el, er, row_start, csr_src, b1, h1h, N);

    // layer 2: in=64(fp16), M=64 (cols 40-63 exact zeros), H=1
    gemm_mfma<64, 64, 1, true><<<mgrid, 256, 0, stream>>>(h1h, Wp2, al2p, ar2p, feat, el, er, N);
    gat_aggregate3<1, 40, 64, 8, false><<<pgrid, 256, 0, stream>>>(feat, el, er, row_start, csr_src, b2, out, N);
}

// Round 10
// 265.133 us; speedup vs baseline: 1.1492x; 1.0662x over previous
//
#include <hip/hip_runtime.h>
#include <hip/hip_fp16.h>
#include <math.h>

#define NEG_SLOPE 0.2f

typedef _Float16 h8 __attribute__((ext_vector_type(8)));
typedef float f4 __attribute__((ext_vector_type(4)));

// ---------------- fp16 pack/unpack helpers ----------------

__device__ inline float2 up2(unsigned u) {
    __half2 h;
    __builtin_memcpy(&h, &u, 4);
    return __half22float2(h);
}
__device__ inline unsigned pk2(float a, float b) {
    __half2 h = __floats2half2_rn(a, b);
    unsigned u;
    __builtin_memcpy(&u, &h, 4);
    return u;
}
__device__ inline void fma8(float* acc, const uint4& v, float p) {
    float2 f;
    f = up2(v.x); acc[0] += f.x * p; acc[1] += f.y * p;
    f = up2(v.y); acc[2] += f.x * p; acc[3] += f.y * p;
    f = up2(v.z); acc[4] += f.x * p; acc[5] += f.y * p;
    f = up2(v.w); acc[6] += f.x * p; acc[7] += f.y * p;
}
__device__ inline float dot4(const float4& a, const float4& b) {
    return a.x * b.x + a.y * b.y + a.z * b.z + a.w * b.w;
}

// ---------------- prep: zero deg + pack W (fp16 fragment-major) + pad al2/ar2 ----
// W element (k,m): cfrag c=m>>4, kstep s=k>>5, lane=((k>>3)&3)*16 + (m&15), j=k&7

__global__ __launch_bounds__(256) void prep(const float* __restrict__ W0,
                                            const float* __restrict__ W1,
                                            const float* __restrict__ W2,
                                            const float* __restrict__ al2,
                                            const float* __restrict__ ar2,
                                            __half* __restrict__ P0,
                                            __half* __restrict__ P1,
                                            __half* __restrict__ P2,
                                            float* __restrict__ al2p,
                                            float* __restrict__ ar2p,
                                            int* __restrict__ deg, int N) {
    int b = blockIdx.x;
    int gtid = b * 256 + threadIdx.x;
    for (int i = gtid; i < N; i += gridDim.x * 256) deg[i] = 0;

    if (b < 14) {
        const float* W;
        __half* P;
        int K, M, Msrc, lb = b;
        if (lb < 8) {
            W = W0; P = P0; K = 128; M = 128; Msrc = 128;
        } else if (lb < 12) {
            W = W1; P = P1; K = 128; M = 64; Msrc = 64; lb -= 8;
        } else {
            W = W2; P = P2; K = 64; M = 64; Msrc = 40; lb -= 12;
        }
        int t = lb * 256 + threadIdx.x;  // indexes (m, k8)
        int nk8 = K >> 3;
        if (t < M * nk8) {
            int m = t % M, k8 = t / M;
            int k = k8 * 8;
            int c = m >> 4, s = k >> 5, hi = (k >> 3) & 3, lane = hi * 16 + (m & 15);
            float v[8];
#pragma unroll
            for (int i = 0; i < 8; ++i)
                v[i] = (m < Msrc) ? W[(size_t)(k + i) * Msrc + m] : 0.f;
            uint4 o;
            o.x = pk2(v[0], v[1]);
            o.y = pk2(v[2], v[3]);
            o.z = pk2(v[4], v[5]);
            o.w = pk2(v[6], v[7]);
            *(uint4*)(P + (size_t)((c * (K >> 5) + s) * 64 + lane) * 8) = o;
        }
    } else if (b == 14) {
        int t = threadIdx.x;
        if (t < 64) {
            al2p[t] = (t < 40) ? al2[t] : 0.f;
            ar2p[t] = (t < 40) ? ar2[t] : 0.f;
        }
    }
}

// ---------------- CSR build ----------------

__global__ __launch_bounds__(256) void degree_hist_rank(const int* __restrict__ dst,
                                                        int* __restrict__ deg,
                                                        int* __restrict__ rank, int E) {
    int e = blockIdx.x * blockDim.x + threadIdx.x;
    if (e >= E) return;
    int d = __builtin_nontemporal_load(&dst[e]);
    int r = atomicAdd(&deg[d], 1);
    __builtin_nontemporal_store(r, &rank[e]);
}

__global__ __launch_bounds__(256) void scan_block_sums(const int* __restrict__ in,
                                                       int* __restrict__ partial, int n) {
    int i = blockIdx.x * 256 + threadIdx.x;
    int v = (i < n) ? in[i] : 0;
#pragma unroll
    for (int off = 32; off; off >>= 1) v += __shfl_xor(v, off);
    __shared__ int wsum[4];
    if ((threadIdx.x & 63) == 0) wsum[threadIdx.x >> 6] = v;
    __syncthreads();
    if (threadIdx.x == 0) partial[blockIdx.x] = wsum[0] + wsum[1] + wsum[2] + wsum[3];
}

// merged offsets+final scan; each block reduces partial[0..bid) itself (nb<=256).
__global__ __launch_bounds__(256) void scan_final2(const int* __restrict__ in,
                                                   const int* __restrict__ partial,
                                                   int* __restrict__ out, int n) {
    __shared__ int buf[256];
    __shared__ int wsum[4];
    int t = threadIdx.x;
    int i = blockIdx.x * 256 + t;
    int v = (i < n) ? in[i] : 0;
    buf[t] = v;
    __syncthreads();
    for (int off = 1; off < 256; off <<= 1) {
        int x = (t >= off) ? buf[t - off] : 0;
        __syncthreads();
        buf[t] += x;
        __syncthreads();
    }
    int incl = buf[t];
    int pv = (t < blockIdx.x) ? partial[t] : 0;
#pragma unroll
    for (int off = 32; off; off >>= 1) pv += __shfl_xor(pv, off);
    if ((t & 63) == 0) wsum[t >> 6] = pv;
    __syncthreads();
    int pre = wsum[0] + wsum[1] + wsum[2] + wsum[3];
    if (i < n) out[i] = pre + incl - v;
    if (i == n - 1) out[n] = pre + incl;
}

__global__ __launch_bounds__(256) void scatter_rank(const int* __restrict__ src,
                                                    const int* __restrict__ dst,
                                                    const int* __restrict__ rank,
                                                    const int* __restrict__ row_start,
                                                    int* __restrict__ csr_src, int E) {
    int e = blockIdx.x * blockDim.x + threadIdx.x;
    if (e >= E) return;
    int d = __builtin_nontemporal_load(&dst[e]);
    int s = __builtin_nontemporal_load(&src[e]);
    int r = __builtin_nontemporal_load(&rank[e]);
    csr_src[row_start[d] + r] = s;
}

// ---------------- MFMA GEMM + fused attn-score epilogue ----------------
// 4 waves/block, 16 rows/wave, 64 rows/block. B fragments read straight from
// packed global W (L1/L2 resident); no inter-wave LDS sharing -> no barriers.
// A frag: row=lane&15, k=(lane>>4)*8+j.  D frag: col=lane&15, row=(lane>>4)*4+r.

template <int K, int M, int H, bool A16>
__global__ __launch_bounds__(256) void gemm_mfma(const void* __restrict__ xin,
                                                 const __half* __restrict__ Wp,
                                                 const float* __restrict__ al,
                                                 const float* __restrict__ ar,
                                                 __half* __restrict__ outh,
                                                 float* __restrict__ el,
                                                 float* __restrict__ er, int N) {
    constexpr int KS = K / 32;   // k-steps
    constexpr int CF = M / 16;   // column fragments
    constexpr int LDT = 133;     // padded fp32 LDS row stride
    constexpr int CH8 = M / 8;   // 8-col chunks per row
    constexpr int NC8 = CH8 / 4; // chunks per lane in read-back (4 lanes/row)
    __shared__ float tl[4 * 16 * LDT];
    const int tid = threadIdx.x;
    const int wid = tid >> 6, lane = tid & 63;
    const int lhi = lane >> 4, llo = lane & 15;
    const int rowbase = blockIdx.x * 64 + wid * 16;
    float* wt = tl + wid * 16 * LDT;

    f4 acc[CF];
#pragma unroll
    for (int c = 0; c < CF; ++c) acc[c] = f4{0.f, 0.f, 0.f, 0.f};

    const int arow = rowbase + llo;
    const bool aval = arow < N;
#pragma unroll
    for (int s = 0; s < KS; ++s) {
        h8 a = {};
        if (aval) {
            if constexpr (A16) {
                const __half* xp = (const __half*)xin + (size_t)arow * K + s * 32 + lhi * 8;
                a = *(const h8*)xp;
            } else {
                const float4* xp = (const float4*)((const float*)xin + (size_t)arow * K +
                                                   s * 32 + lhi * 8);
                float4 x0 = xp[0];
                float4 x1 = xp[1];
                a[0] = (_Float16)x0.x; a[1] = (_Float16)x0.y;
                a[2] = (_Float16)x0.z; a[3] = (_Float16)x0.w;
                a[4] = (_Float16)x1.x; a[5] = (_Float16)x1.y;
                a[6] = (_Float16)x1.z; a[7] = (_Float16)x1.w;
            }
        }
#pragma unroll
        for (int c = 0; c < CF; ++c) {
            h8 b = *(const h8*)(Wp + (size_t)((c * KS + s) * 64 + lane) * 8);
            acc[c] = __builtin_amdgcn_mfma_f32_16x16x32_f16(a, b, acc[c], 0, 0, 0);
        }
    }

    // scatter D frags into the per-wave LDS tile (row = lhi*4+r, col = c*16+llo)
#pragma unroll
    for (int c = 0; c < CF; ++c) {
#pragma unroll
        for (int r = 0; r < 4; ++r)
            wt[(lhi * 4 + r) * LDT + c * 16 + llo] = acc[c][r];
    }

    // read back row-major: 4 lanes per row, interleaved 8-col chunks j8 = q + 4*i
    const int rrow = lane >> 2;
    const int q = lane & 3;
    const int grow = rowbase + rrow;
    float elp[H], erp[H];
#pragma unroll
    for (int h = 0; h < H; ++h) { elp[h] = 0.f; erp[h] = 0.f; }
    const float4* al4 = (const float4*)al;
    const float4* ar4 = (const float4*)ar;
#pragma unroll
    for (int i = 0; i < NC8; ++i) {
        int j8 = q + 4 * i;
        float4 v0 = *(float4*)&wt[rrow * LDT + 8 * j8];
        float4 v1 = *(float4*)&wt[rrow * LDT + 8 * j8 + 4];
        int h = (H == 2 && i >= NC8 / 2) ? 1 : 0;
        float4 a0 = al4[2 * j8], a1 = al4[2 * j8 + 1];
        float4 r0 = ar4[2 * j8], r1 = ar4[2 * j8 + 1];
        elp[h] += dot4(v0, a0) + dot4(v1, a1);
        erp[h] += dot4(v0, r0) + dot4(v1, r1);
        if (grow < N) {
            uint4 pkv;
            pkv.x = pk2(v0.x, v0.y);
            pkv.y = pk2(v0.z, v0.w);
            pkv.z = pk2(v1.x, v1.y);
            pkv.w = pk2(v1.z, v1.w);
            *(uint4*)(outh + (size_t)grow * M + 8 * j8) = pkv;
        }
    }
#pragma unroll
    for (int h = 0; h < H; ++h) {
#pragma unroll
        for (int off = 1; off < 4; off <<= 1) {
            elp[h] += __shfl_xor(elp[h], off);
            erp[h] += __shfl_xor(erp[h], off);
        }
    }
    if (q == 0 && grow < N) {
        if constexpr (H == 2) {
            *(float2*)&el[(size_t)grow * 2] = float2{elp[0], elp[1]};
            *(float2*)&er[(size_t)grow * 2] = float2{erp[0], erp[1]};
        } else {
            el[grow] = elp[0];
            er[grow] = erp[0];
        }
    }
}

// ---------------- per-dst softmax + aggregation (HALF-wave per dst) ----------------
// Latency-overlap order per 32-edge trip:
//   (1) issue el[s] load (oldest outstanding vmem)
//   (2) issue ALL feature-row gathers for the trip (BATCH == 32)
//   (3) compute p  -> waits only el (vmcnt(T)), gathers still in flight
//   (4) fma        -> waits gathers (vmcnt(0))
// One memory-latency exposure per trip instead of two/three.

template <int H, int D, int FSTRIDE, int T, bool OUT16>
__global__ __launch_bounds__(256) void gat_aggregate3(const __half* __restrict__ feat,
                                                      const float* __restrict__ el,
                                                      const float* __restrict__ er,
                                                      const int* __restrict__ row_start,
                                                      const int* __restrict__ csr_src,
                                                      const float* __restrict__ bias,
                                                      void* __restrict__ out, int N) {
    constexpr int NLp = FSTRIDE / 8;   // lanes per padded row (uint4 each)
    constexpr int GnH = 32 / NLp;      // edge groups per half-wave
    constexpr int BATCH = GnH * T;     // edges per gather round per half
    constexpr int WL = (H * D) / 8;    // writer lanes per dst
    static_assert(32 % NLp == 0 && BATCH == 32, "whole trip in one round");
    int pair = (blockIdx.x * blockDim.x + threadIdx.x) >> 6;
    int lane = threadIdx.x & 63;
    if (pair * 2 >= N) return;
    const int l32 = lane & 31;
    const int hb = lane & 32;
    const int dstn = pair * 2 + (lane >> 5);
    const bool dval = dstn < N;
    int beg = dval ? row_start[dstn] : 0;
    int end = dval ? row_start[dstn + 1] : 0;
    int cnt = end - beg;

    float er_d[H];
#pragma unroll
    for (int h = 0; h < H; ++h) er_d[h] = dval ? er[(size_t)dstn * H + h] : 0.f;

    float ssum[H];
    float acc8[8];
#pragma unroll
    for (int h = 0; h < H; ++h) ssum[h] = 0.f;
#pragma unroll
    for (int i = 0; i < 8; ++i) acc8[i] = 0.f;

    const int g = l32 / NLp;
    const int ln = l32 % NLp;
    const uint4* fp = (const uint4*)feat;

    int trips = (cnt + 31) >> 5;
    {
        int to = __shfl_xor(trips, 32);
        trips = (to > trips) ? to : trips;
    }

    for (int it = 0; it < trips; ++it) {
        int base = beg + it * 32;
        int idx = base + l32;
        bool valid = idx < end;
        int s = csr_src[valid ? idx : beg];
        int cc = end - base;
        cc = (cc < 0) ? 0 : ((cc > 32) ? 32 : cc);

        // (1) score-input load first: oldest outstanding vmem op
        float ev0 = 0.f, ev1 = 0.f;
        if constexpr (H == 2) {
            float2 e2 = ((const float2*)el)[s];
            ev0 = e2.x;
            ev1 = e2.y;
        } else {
            ev0 = el[s];
        }

        // (2) issue the whole trip's feature-row gathers (depend only on s)
        uint4 v[T];
#pragma unroll
        for (int t = 0; t < T; ++t) {
            if (GnH * t < cc) {
                int sj = __shfl(s, hb + GnH * t + g);
                v[t] = fp[(size_t)sj * NLp + ln];
            }
        }

        // (3) scores: waits only on el (gathers remain in flight)
        float p[H];
        if constexpr (H == 2) {
            float e0 = ev0 + er_d[0];
            float e1 = ev1 + er_d[1];
            e0 = (e0 > 0.f) ? e0 : NEG_SLOPE * e0;
            e1 = (e1 > 0.f) ? e1 : NEG_SLOPE * e1;
            p[0] = valid ? __expf(e0) : 0.f;
            p[1] = valid ? __expf(e1) : 0.f;
            ssum[0] += p[0];
            ssum[1] += p[1];
        } else {
            float e = ev0 + er_d[0];
            e = (e > 0.f) ? e : NEG_SLOPE * e;
            p[0] = valid ? __expf(e) : 0.f;
            ssum[0] += p[0];
        }

        // (4) weighted accumulate
#pragma unroll
        for (int t = 0; t < T; ++t) {
            if (GnH * t < cc) {
                int slot = hb + GnH * t + g;
                float pj = __shfl(p[0], slot);
                if constexpr (H == 2) {
                    float pj1 = __shfl(p[1], slot);
                    pj = (ln >= 8) ? pj1 : pj;
                }
                fma8(acc8, v[t], pj);
            }
        }
    }

#pragma unroll
    for (int h = 0; h < H; ++h)
#pragma unroll
        for (int off = 16; off; off >>= 1) ssum[h] += __shfl_xor(ssum[h], off);
#pragma unroll
    for (int i = 0; i < 8; ++i) {
#pragma unroll
        for (int off = NLp; off < 32; off <<= 1) acc8[i] += __shfl_xor(acc8[i], off);
    }
    if (l32 < WL && dval) {
        float inv;
        if constexpr (H == 2) inv = 1.f / ((l32 >= 8) ? ssum[1] : ssum[0]);
        else inv = 1.f / ssum[0];
        const float4* bp = (const float4*)bias;
        float4 bv0 = bp[2 * l32], bv1 = bp[2 * l32 + 1];
        float4 o0, o1;
        o0.x = acc8[0] * inv + bv0.x; o0.y = acc8[1] * inv + bv0.y;
        o0.z = acc8[2] * inv + bv0.z; o0.w = acc8[3] * inv + bv0.w;
        o1.x = acc8[4] * inv + bv1.x; o1.y = acc8[5] * inv + bv1.y;
        o1.z = acc8[6] * inv + bv1.z; o1.w = acc8[7] * inv + bv1.w;
        if constexpr (OUT16) {
            __half* op = (__half*)out + (size_t)dstn * (H * D);
            uint4 pkv;
            pkv.x = pk2(o0.x, o0.y);
            pkv.y = pk2(o0.z, o0.w);
            pkv.z = pk2(o1.x, o1.y);
            pkv.w = pk2(o1.z, o1.w);
            ((uint4*)op)[l32] = pkv;
        } else {
            float4* op = (float4*)((float*)out + (size_t)dstn * (H * D));
            op[2 * l32] = o0;
            op[2 * l32 + 1] = o1;
        }
    }
}

// ---------------- launch ----------------

extern "C" void kernel_launch(void* const* d_in, const int* in_sizes, int n_in,
                              void* d_out, int out_size, void* d_ws, size_t ws_size,
                              hipStream_t stream) {
    const float* in_feat = (const float*)d_in[0];
    const int*   src     = (const int*)d_in[1];
    const int*   dst     = (const int*)d_in[2];
    const float* W0 = (const float*)d_in[3];
    const float* al0 = (const float*)d_in[4];
    const float* ar0 = (const float*)d_in[5];
    const float* b0 = (const float*)d_in[6];
    const float* W1 = (const float*)d_in[7];
    const float* al1 = (const float*)d_in[8];
    const float* ar1 = (const float*)d_in[9];
    const float* b1 = (const float*)d_in[10];
    const float* W2 = (const float*)d_in[11];
    const float* al2 = (const float*)d_in[12];
    const float* ar2 = (const float*)d_in[13];
    const float* b2 = (const float*)d_in[14];
    float* out = (float*)d_out;

    const int N = in_sizes[0] / 128;  // 50000
    const int E = in_sizes[1];        // 850000

    char* ws = (char*)d_ws;
    auto alloc = [&](size_t bytes) -> void* {
        void* p = (void*)ws;
        ws += (bytes + 255) & ~(size_t)255;
        return p;
    };
    int* deg       = (int*)alloc((size_t)N * 4);
    int* row_start = (int*)alloc((size_t)(N + 1) * 4);
    int* csr_src   = (int*)alloc((size_t)E * 4);
    int* rank      = (int*)alloc((size_t)E * 4);
    int* partial   = (int*)alloc(256 * 4);
    __half* feat   = (__half*)alloc((size_t)N * 128 * 2);
    float* el      = (float*)alloc((size_t)N * 2 * 4);
    float* er      = (float*)alloc((size_t)N * 2 * 4);
    __half* h0h    = (__half*)alloc((size_t)N * 128 * 2);
    __half* h1h    = (__half*)alloc((size_t)N * 64 * 2);
    __half* Wp0    = (__half*)alloc((size_t)128 * 128 * 2);
    __half* Wp1    = (__half*)alloc((size_t)128 * 64 * 2);
    __half* Wp2    = (__half*)alloc((size_t)64 * 64 * 2);
    float* al2p    = (float*)alloc(64 * 4);
    float* ar2p    = (float*)alloc(64 * 4);

    int egrid = (E + 255) / 256;
    int nb = (N + 255) / 256;

    prep<<<256, 256, 0, stream>>>(W0, W1, W2, al2, ar2, Wp0, Wp1, Wp2, al2p, ar2p, deg, N);
    degree_hist_rank<<<egrid, 256, 0, stream>>>(dst, deg, rank, E);
    scan_block_sums<<<nb, 256, 0, stream>>>(deg, partial, N);
    scan_final2<<<nb, 256, 0, stream>>>(deg, partial, row_start, N);
    scatter_rank<<<egrid, 256, 0, stream>>>(src, dst, rank, row_start, csr_src, E);

    int npairs = (N + 1) / 2;
    int pgrid = (npairs * 64 + 255) / 256;  // one wave per dst-pair
    int mgrid = (N + 63) / 64;              // 64 rows per MFMA gemm block

    // layer 0: in=128(fp32), M=128, H=2  | agg: FSTRIDE=128 -> T=16 (BATCH=32)
    gemm_mfma<128, 128, 2, false><<<mgrid, 256, 0, stream>>>(in_feat, Wp0, al0, ar0, feat, el, er, N);
    gat_aggregate3<2, 64, 128, 16, true><<<pgrid, 256, 0, stream>>>(feat, el, er, row_start, csr_src, b0, h0h, N);

    // layer 1: in=128(fp16), M=64, H=1   | agg: FSTRIDE=64 -> T=8 (BATCH=32)
    gemm_mfma<128, 64, 1, true><<<mgrid, 256, 0, stream>>>(h0h, Wp1, al1, ar1, feat, el, er, N);
    gat_aggregate3<1, 64, 64, 8, true><<<pgrid, 256, 0, stream>>>(feat, el, er, row_start, csr_src, b1, h1h, N);

    // layer 2: in=64(fp16), M=64 (cols 40-63 exact zeros), H=1
    gemm_mfma<64, 64, 1, true><<<mgrid, 256, 0, stream>>>(h1h, Wp2, al2p, ar2p, feat, el, er, N);
    gat_aggregate3<1, 40, 64, 8, false><<<pgrid, 256, 0, stream>>>(feat, el, er, row_start, csr_src, b2, out, N);
}